// Round 5
// baseline (105.730 us; speedup 1.0000x reference)
//
#include <hip/hip_runtime.h>
#include <math.h>

#define BB 32
#define NN 2048
#define DD 2048
#define KK 5
#define RPW 8   // rows per wave

typedef float fx4 __attribute__((ext_vector_type(4)));

// Kernel 1: scores[row] = dot(value[row, :], w).
// One wave per 8 consecutive rows; loads interleaved across rows (8 independent
// chains, 32 fx4 loads in flight); w in registers; all shuffle reduces at the end.
__global__ __launch_bounds__(256) void score_kernel(const float* __restrict__ value,
                                                    const float* __restrict__ w,
                                                    float* __restrict__ scores) {
    const int lane  = threadIdx.x & 63;
    const int gwave = (blockIdx.x * blockDim.x + threadIdx.x) >> 6;

    const fx4* w4 = reinterpret_cast<const fx4*>(w);
    fx4 wr[8];
#pragma unroll
    for (int i = 0; i < 8; ++i) wr[i] = w4[i * 64 + lane];

    const int row0 = gwave * RPW;
    const fx4* base = reinterpret_cast<const fx4*>(value + (size_t)row0 * DD) + lane;

    float acc[RPW];
#pragma unroll
    for (int r = 0; r < RPW; ++r) acc[r] = 0.f;

#pragma unroll
    for (int i = 0; i < 8; ++i) {              // chunk within row
#pragma unroll
        for (int r = 0; r < RPW; ++r) {        // 8 independent chains
            fx4 v = __builtin_nontemporal_load(&base[(size_t)r * (DD / 4) + i * 64]);
            acc[r] += v.x * wr[i].x + v.y * wr[i].y + v.z * wr[i].z + v.w * wr[i].w;
        }
    }

#pragma unroll
    for (int r = 0; r < RPW; ++r) {
        float a = acc[r];
#pragma unroll
        for (int off = 32; off > 0; off >>= 1)
            a += __shfl_down(a, off, 64);
        if (lane == 0) scores[row0 + r] = a;
    }
}

// Kernel 2a: per-batch top-5 indices (descending, lowest-index tie-break).
// One block of 256 threads per batch; writes sel[b][k] to ws.
__global__ __launch_bounds__(256) void topk_kernel(const float* __restrict__ scores,
                                                   int* __restrict__ sel_out) {
    __shared__ float s[NN];
    __shared__ float wbest[4];
    __shared__ int   wbesti[4];

    const int b    = blockIdx.x;
    const int tid  = threadIdx.x;
    const int lane = tid & 63;
    const int wv   = tid >> 6;

    for (int i = tid; i < NN; i += 256) s[i] = scores[b * NN + i];
    __syncthreads();

    for (int k = 0; k < KK; ++k) {
        float bv = -INFINITY;
        int   bi = 0x7fffffff;
        for (int i = tid; i < NN; i += 256) {
            float v = s[i];
            if (v > bv) { bv = v; bi = i; }   // i increasing per thread: ties keep lowest i
        }
#pragma unroll
        for (int off = 32; off > 0; off >>= 1) {
            float ov = __shfl_down(bv, off, 64);
            int   oi = __shfl_down(bi, off, 64);
            if (ov > bv || (ov == bv && oi < bi)) { bv = ov; bi = oi; }
        }
        if (lane == 0) { wbest[wv] = bv; wbesti[wv] = bi; }
        __syncthreads();
        if (tid == 0) {
            float fv = wbest[0]; int fi = wbesti[0];
#pragma unroll
            for (int j = 1; j < 4; ++j) {
                if (wbest[j] > fv || (wbest[j] == fv && wbesti[j] < fi)) {
                    fv = wbest[j]; fi = wbesti[j];
                }
            }
            sel_out[b * KK + k] = fi;
            s[fi] = -INFINITY;
        }
        __syncthreads();
    }
}

// Kernel 2b: gather. One block per (b,k): out[b,k,:] = value[b, sel[b][k], :].
__global__ __launch_bounds__(256) void gather_kernel(const int* __restrict__ sel,
                                                     const float* __restrict__ value,
                                                     float* __restrict__ out) {
    const int bk  = blockIdx.x;          // 0 .. B*KK-1
    const int b   = bk / KK;
    const int tid = threadIdx.x;
    const int idx = sel[bk];

    const float4* src = reinterpret_cast<const float4*>(value + ((size_t)b * NN + idx) * DD);
    float4*       dst = reinterpret_cast<float4*>(out + (size_t)bk * DD);
#pragma unroll
    for (int i = 0; i < DD / 4 / 256; ++i)   // 2 iters
        dst[i * 256 + tid] = src[i * 256 + tid];
}

extern "C" void kernel_launch(void* const* d_in, const int* in_sizes, int n_in,
                              void* d_out, int out_size, void* d_ws, size_t ws_size,
                              hipStream_t stream) {
    const float* value = (const float*)d_in[0];
    const float* w     = (const float*)d_in[1];
    // d_in[2] = b (additive constant, irrelevant to top-k and gathered values)
    // d_in[3] = num_cxt (fixed at 5)
    float* scores = (float*)d_ws;                       // B*N floats = 256 KB
    int*   sel    = (int*)((char*)d_ws + (size_t)BB * NN * sizeof(float));  // B*KK ints
    float* out    = (float*)d_out;

    const int waves  = (BB * NN) / RPW;   // 8192 waves
    const int blocks = waves / 4;         // 2048 blocks of 256 threads
    score_kernel<<<blocks, 256, 0, stream>>>(value, w, scores);
    topk_kernel<<<BB, 256, 0, stream>>>(scores, sel);
    gather_kernel<<<BB * KK, 256, 0, stream>>>(sel, value, out);
}

// Round 6
// 91.980 us; speedup vs baseline: 1.1495x; 1.1495x over previous
//
#include <hip/hip_runtime.h>
#include <math.h>

#define BB 32
#define NN 2048
#define DD 2048
#define KK 5
#define RPW 4   // rows per wave (R4-proven best: 4)

typedef float fx4 __attribute__((ext_vector_type(4)));

// Kernel 1: scores[row] = dot(value[row, :], w).  (R4 configuration, 92.1 us)
// One wave per 4 consecutive rows; loads interleaved across rows (4 independent
// chains); w in registers; all shuffle reduces at the end.
__global__ __launch_bounds__(256) void score_kernel(const float* __restrict__ value,
                                                    const float* __restrict__ w,
                                                    float* __restrict__ scores) {
    const int lane  = threadIdx.x & 63;
    const int gwave = (blockIdx.x * blockDim.x + threadIdx.x) >> 6;

    const fx4* w4 = reinterpret_cast<const fx4*>(w);
    fx4 wr[8];
#pragma unroll
    for (int i = 0; i < 8; ++i) wr[i] = w4[i * 64 + lane];

    const int row0 = gwave * RPW;
    const fx4* vrow[RPW];
#pragma unroll
    for (int r = 0; r < RPW; ++r)
        vrow[r] = reinterpret_cast<const fx4*>(value + (size_t)(row0 + r) * DD) + lane;

    float acc[RPW] = {0.f, 0.f, 0.f, 0.f};
#pragma unroll
    for (int i = 0; i < 8; ++i) {          // chunk index within row
#pragma unroll
        for (int r = 0; r < RPW; ++r) {    // 4 independent load chains
            fx4 v = __builtin_nontemporal_load(&vrow[r][i * 64]);
            acc[r] += v.x * wr[i].x + v.y * wr[i].y + v.z * wr[i].z + v.w * wr[i].w;
        }
    }

#pragma unroll
    for (int r = 0; r < RPW; ++r) {
        float a = acc[r];
#pragma unroll
        for (int off = 32; off > 0; off >>= 1)
            a += __shfl_down(a, off, 64);
        if (lane == 0) scores[row0 + r] = a;
    }
}

// Kernel 2a: per-batch top-5 indices (descending, lowest-index tie-break).
// One block of 256 threads per batch; writes sel[b][k] to ws.
__global__ __launch_bounds__(256) void topk_kernel(const float* __restrict__ scores,
                                                   int* __restrict__ sel_out) {
    __shared__ float s[NN];
    __shared__ float wbest[4];
    __shared__ int   wbesti[4];

    const int b    = blockIdx.x;
    const int tid  = threadIdx.x;
    const int lane = tid & 63;
    const int wv   = tid >> 6;

    for (int i = tid; i < NN; i += 256) s[i] = scores[b * NN + i];
    __syncthreads();

    for (int k = 0; k < KK; ++k) {
        float bv = -INFINITY;
        int   bi = 0x7fffffff;
        for (int i = tid; i < NN; i += 256) {
            float v = s[i];
            if (v > bv) { bv = v; bi = i; }   // i increasing per thread: ties keep lowest i
        }
#pragma unroll
        for (int off = 32; off > 0; off >>= 1) {
            float ov = __shfl_down(bv, off, 64);
            int   oi = __shfl_down(bi, off, 64);
            if (ov > bv || (ov == bv && oi < bi)) { bv = ov; bi = oi; }
        }
        if (lane == 0) { wbest[wv] = bv; wbesti[wv] = bi; }
        __syncthreads();
        if (tid == 0) {
            float fv = wbest[0]; int fi = wbesti[0];
#pragma unroll
            for (int j = 1; j < 4; ++j) {
                if (wbest[j] > fv || (wbest[j] == fv && wbesti[j] < fi)) {
                    fv = wbest[j]; fi = wbesti[j];
                }
            }
            sel_out[b * KK + k] = fi;
            s[fi] = -INFINITY;
        }
        __syncthreads();
    }
}

// Kernel 2b: gather. One block per (b,k): out[b,k,:] = value[b, sel[b][k], :].
__global__ __launch_bounds__(256) void gather_kernel(const int* __restrict__ sel,
                                                     const float* __restrict__ value,
                                                     float* __restrict__ out) {
    const int bk  = blockIdx.x;          // 0 .. B*KK-1
    const int b   = bk / KK;
    const int tid = threadIdx.x;
    const int idx = sel[bk];

    const float4* src = reinterpret_cast<const float4*>(value + ((size_t)b * NN + idx) * DD);
    float4*       dst = reinterpret_cast<float4*>(out + (size_t)bk * DD);
#pragma unroll
    for (int i = 0; i < DD / 4 / 256; ++i)   // 2 iters
        dst[i * 256 + tid] = src[i * 256 + tid];
}

extern "C" void kernel_launch(void* const* d_in, const int* in_sizes, int n_in,
                              void* d_out, int out_size, void* d_ws, size_t ws_size,
                              hipStream_t stream) {
    const float* value = (const float*)d_in[0];
    const float* w     = (const float*)d_in[1];
    // d_in[2] = b (additive constant, irrelevant to top-k and gathered values)
    // d_in[3] = num_cxt (fixed at 5)
    float* scores = (float*)d_ws;                       // B*N floats = 256 KB
    int*   sel    = (int*)((char*)d_ws + (size_t)BB * NN * sizeof(float));  // B*KK ints
    float* out    = (float*)d_out;

    const int waves  = (BB * NN) / RPW;   // 16384 waves
    const int blocks = waves / 4;         // 4096 blocks of 256 threads
    score_kernel<<<blocks, 256, 0, stream>>>(value, w, scores);
    topk_kernel<<<BB, 256, 0, stream>>>(scores, sel);
    gather_kernel<<<BB * KK, 256, 0, stream>>>(sel, value, out);
}